// Round 8
// baseline (511.692 us; speedup 1.0000x reference)
//
#include <hip/hip_runtime.h>
#include <cstdint>
#include <cstddef>

// ---------------------------------------------------------------------------
// ASD_RNN round 8: register-resident-Wh persistent LSTM (32 blocks x 512 thr,
// no LDS in step loop), padded per-block flags, fused prep kernel.
// B=64, S=64, F_IN=2048, H=512, 4H=2048, P2=20.
// ---------------------------------------------------------------------------

typedef __attribute__((ext_vector_type(8))) short short8;
typedef __attribute__((ext_vector_type(4))) float f32x4;
typedef unsigned long long ull;

__device__ __forceinline__ ushort f2bf(float x) {
    uint32_t u = __float_as_uint(x);
    return (ushort)((u + 0x7FFF + ((u >> 16) & 1)) >> 16);   // RNE
}
__device__ __forceinline__ float bf2f(ushort u) {
    return __uint_as_float(((uint32_t)u) << 16);
}
__device__ __forceinline__ float sigm(float x) { return 1.f / (1.f + expf(-x)); }
__device__ __forceinline__ float tanh_fast(float x) { return 2.f / (1.f + expf(-2.f * x)) - 1.f; }

// ---------------------------------------------------------------------------
// k_prep: all independent pre-processing in one launch (block-range dispatch).
//   [0,8192)      : v_feat fp32 -> bf16 (4 elems/thread)
//   [8192,8232)   : proto fp32 -> bf16
//   [8232,8240)   : bxh[n'] = bx[n]+bh[n] (n' remap)
//   [8240,9264)   : W_enc^T -> Wenc_t [512][2048] (no remap)
//   [9264,10288)  : Wx^T -> Wx_t [2048][512] (n' remap)
//   [10288,11312) : Wh^T -> Whr [2048][512] (n' remap)
//   [11312,12336) : rowstats (n2 + g_logit partials)
//   [12336]       : p2
// ---------------------------------------------------------------------------
__global__ __launch_bounds__(256) void k_prep(
    const float* __restrict__ v_feat, const float* __restrict__ proto,
    const float* __restrict__ bx, const float* __restrict__ bh,
    const float* __restrict__ W_enc, const float* __restrict__ Wx,
    const float* __restrict__ Wh, const float* __restrict__ W_gate,
    ushort* __restrict__ v_bf16, ushort* __restrict__ proto_bf,
    float* __restrict__ bxh, ushort* __restrict__ Wenc_t,
    ushort* __restrict__ Wx_t, ushort* __restrict__ Whr,
    float* __restrict__ n2, float* __restrict__ g_logit, float* __restrict__ p2)
{
    __shared__ float ts[32][33];
    const int blk = blockIdx.x;
    const int tid = threadIdx.x;

    if (blk < 8192) {                               // v convert
        int i = blk * 256 + tid;
        float4 v = ((const float4*)v_feat)[i];
        ushort4 o;
        o.x = f2bf(v.x); o.y = f2bf(v.y); o.z = f2bf(v.z); o.w = f2bf(v.w);
        ((ushort4*)v_bf16)[i] = o;
    } else if (blk < 8232) {                        // proto convert
        int i = (blk - 8192) * 256 + tid;
        float4 v = ((const float4*)proto)[i];
        ushort4 o;
        o.x = f2bf(v.x); o.y = f2bf(v.y); o.z = f2bf(v.z); o.w = f2bf(v.w);
        ((ushort4*)proto_bf)[i] = o;
    } else if (blk < 8240) {                        // bias remap
        int n = (blk - 8232) * 256 + tid;
        int np = ((n & 511) << 2) | (n >> 9);
        bxh[np] = bx[n] + bh[n];
    } else if (blk < 11312) {                       // the three transposes
        const float* in;
        ushort* outp;
        int R, C, remap, t;
        if (blk < 9264)       { in = W_enc; outp = Wenc_t; R = 2048; C = 512;  remap = 0; t = blk - 8240; }
        else if (blk < 10288) { in = Wx;    outp = Wx_t;   R = 512;  C = 2048; remap = 1; t = blk - 9264; }
        else                  { in = Wh;    outp = Whr;    R = 512;  C = 2048; remap = 1; t = blk - 10288; }
        int tpr = C / 32;                           // tiles per row of tiles
        int cx = t % tpr, cy = t / tpr;
        int r0 = cy * 32, c0 = cx * 32;
        int rr = tid >> 3, cc = (tid & 7) * 4;
        float4 v = *(const float4*)(in + (size_t)(r0 + rr) * C + c0 + cc);
        ts[rr][cc + 0] = v.x; ts[rr][cc + 1] = v.y; ts[rr][cc + 2] = v.z; ts[rr][cc + 3] = v.w;
        __syncthreads();
        ushort4 o;
        o.x = f2bf(ts[cc + 0][rr]);
        o.y = f2bf(ts[cc + 1][rr]);
        o.z = f2bf(ts[cc + 2][rr]);
        o.w = f2bf(ts[cc + 3][rr]);
        int n = c0 + rr;
        int np = remap ? (((n & 511) << 2) | (n >> 9)) : n;
        *(ushort4*)(outp + (size_t)np * R + r0 + cc) = o;
    } else if (blk < 12336) {                       // rowstats
        const int lane = tid & 63, w = tid >> 6;
        const int bs = (blk - 11312) * 4 + w;
        const float* vr = v_feat + (size_t)bs * 2048;
        float a = 0.f, g = 0.f;
#pragma unroll
        for (int i = 0; i < 8; ++i) {
            float4 x = ((const float4*)vr)[i * 64 + lane];
            float4 wg = ((const float4*)W_gate)[i * 64 + lane];
            a += x.x * x.x + x.y * x.y + x.z * x.z + x.w * x.w;
            g += x.x * wg.x + x.y * wg.y + x.z * wg.z + x.w * wg.w;
        }
#pragma unroll
        for (int o = 32; o > 0; o >>= 1) { a += __shfl_down(a, o); g += __shfl_down(g, o); }
        if (lane == 0) {
            n2[bs] = a;
            atomicAdd(&g_logit[bs >> 6], g);
        }
    } else {                                        // p2 (one block)
        const int lane = tid & 63, w = tid >> 6;
        for (int p = w; p < 20; p += 4) {
            const float* pr = proto + (size_t)p * 2048;
            float a = 0.f;
#pragma unroll
            for (int i = 0; i < 8; ++i) {
                float4 x = ((const float4*)pr)[i * 64 + lane];
                a += x.x * x.x + x.y * x.y + x.z * x.z + x.w * x.w;
            }
#pragma unroll
            for (int o = 32; o > 0; o >>= 1) a += __shfl_down(a, o);
            if (lane == 0) p2[p] = a;
        }
    }
}

// bf16 MFMA GEMM: C[M,N] = A[M,K] @ Bt[N,K]^T. 128x128 tile, 4 waves of 64x64.
// mode 0: fuse (bf16 [M][512]) = relu(acc+bias0[n]) + cat_emb[category[m>>6]][n]
// mode 1: xg (bf16 [s][b][n']) = acc + bias0[n]; m=b*64+s (n axis pre-remapped)
__global__ __launch_bounds__(256) void k_gemm_mfma(
    const ushort* __restrict__ A, const ushort* __restrict__ Bt,
    int M, int N, int K,
    const float* __restrict__ bias0,
    const float* __restrict__ cat_emb, const int* __restrict__ category,
    void* __restrict__ Cout, int mode)
{
    __shared__ ushort As[128][40];
    __shared__ ushort Bs[128][40];
    const int tid = threadIdx.x;
    const int lane = tid & 63, w = tid >> 6;
    const int quad = lane >> 4, l16 = lane & 15;
    const int m0 = blockIdx.y * 128, n0 = blockIdx.x * 128;
    const int wm = (w & 1) * 64, wn = (w >> 1) * 64;

    f32x4 acc[4][4] = {};
    const int lr = tid >> 2;
    const int lc = (tid & 3) * 8;

    for (int k0 = 0; k0 < K; k0 += 32) {
        uint4 a0 = *(const uint4*)(A + (size_t)(m0 + lr) * K + k0 + lc);
        uint4 a1 = *(const uint4*)(A + (size_t)(m0 + 64 + lr) * K + k0 + lc);
        uint4 b0 = *(const uint4*)(Bt + (size_t)(n0 + lr) * K + k0 + lc);
        uint4 b1 = *(const uint4*)(Bt + (size_t)(n0 + 64 + lr) * K + k0 + lc);
        __syncthreads();
        *(uint4*)&As[lr][lc] = a0;
        *(uint4*)&As[64 + lr][lc] = a1;
        *(uint4*)&Bs[lr][lc] = b0;
        *(uint4*)&Bs[64 + lr][lc] = b1;
        __syncthreads();
        short8 af[4], bf[4];
#pragma unroll
        for (int i = 0; i < 4; ++i) af[i] = *(const short8*)&As[wm + i * 16 + l16][quad * 8];
#pragma unroll
        for (int j = 0; j < 4; ++j) bf[j] = *(const short8*)&Bs[wn + j * 16 + l16][quad * 8];
#pragma unroll
        for (int i = 0; i < 4; ++i)
#pragma unroll
            for (int j = 0; j < 4; ++j)
                acc[i][j] = __builtin_amdgcn_mfma_f32_16x16x32_bf16(af[i], bf[j], acc[i][j], 0, 0, 0);
    }

    if (mode == 0) {
        ushort* C = (ushort*)Cout;
#pragma unroll
        for (int i = 0; i < 4; ++i) {
            int mbase = m0 + wm + i * 16 + quad * 4;
#pragma unroll
            for (int r = 0; r < 4; ++r) {
                int m = mbase + r;
                const float* ce = cat_emb + category[m >> 6] * 512;
#pragma unroll
                for (int j = 0; j < 4; ++j) {
                    int n = n0 + wn + j * 16 + l16;
                    float v = fmaxf(acc[i][j][r] + bias0[n], 0.f) + ce[n];
                    C[(size_t)m * 512 + n] = f2bf(v);
                }
            }
        }
    } else {
        ushort* C = (ushort*)Cout;
        float bb[4];
#pragma unroll
        for (int j = 0; j < 4; ++j) bb[j] = bias0[n0 + wn + j * 16 + l16];
#pragma unroll
        for (int i = 0; i < 4; ++i) {
            int mbase = m0 + wm + i * 16 + quad * 4;
#pragma unroll
            for (int r = 0; r < 4; ++r) {
                int m = mbase + r;
                int s = m & 63, b = m >> 6;
                ushort* crow = C + ((size_t)(s * 64 + b)) * 2048;
#pragma unroll
                for (int j = 0; j < 4; ++j)
                    crow[n0 + wn + j * 16 + l16] = f2bf(acc[i][j][r] + bb[j]);
            }
        }
    }
}

// dots[bs][p] = v_bf16[bs][:] . proto_bf[p][:] (proto padded to 32 rows)
__global__ __launch_bounds__(256) void k_dot(const ushort* __restrict__ v_bf,
                                             const ushort* __restrict__ proto_bf,
                                             float* __restrict__ dots)
{
    const int tid = threadIdx.x;
    const int lane = tid & 63, w = tid >> 6;
    const int quad = lane >> 4, l16 = lane & 15;
    const int r0 = blockIdx.x * 64 + w * 16;

    f32x4 acc[2] = {};
    const ushort* arow = v_bf + (size_t)(r0 + l16) * 2048 + quad * 8;
    const ushort* b0p = proto_bf + (size_t)l16 * 2048 + quad * 8;
    const ushort* b1p = proto_bf + (size_t)(16 + l16) * 2048 + quad * 8;
#pragma unroll 8
    for (int kk = 0; kk < 64; ++kk) {
        short8 af = *(const short8*)(arow + kk * 32);
        short8 bf0 = *(const short8*)(b0p + kk * 32);
        short8 bf1 = *(const short8*)(b1p + kk * 32);
        acc[0] = __builtin_amdgcn_mfma_f32_16x16x32_bf16(af, bf0, acc[0], 0, 0, 0);
        acc[1] = __builtin_amdgcn_mfma_f32_16x16x32_bf16(af, bf1, acc[1], 0, 0, 0);
    }
#pragma unroll
    for (int t = 0; t < 2; ++t)
#pragma unroll
        for (int r = 0; r < 4; ++r)
            dots[(size_t)(r0 + quad * 4 + r) * 32 + t * 16 + l16] = acc[t][r];
}

// dd_logit[b] = sum_{s,p} log((d+1)/(d+1e-8)) * W_dd[s*20+p]. grid 64.
__global__ __launch_bounds__(256) void k_dd(const float* __restrict__ dots,
                                            const float* __restrict__ n2,
                                            const float* __restrict__ p2,
                                            const float* __restrict__ W_dd,
                                            float* __restrict__ dd_logit)
{
    __shared__ float red[4];
    const int b = blockIdx.x;
    const int tid = threadIdx.x, lane = tid & 63, w = tid >> 6;
    float acc = 0.f;
    for (int u = tid; u < 1280; u += 256) {
        int s = u / 20, p = u - s * 20;
        int bs = b * 64 + s;
        float d = n2[bs] - 2.f * dots[(size_t)bs * 32 + p] + p2[p];
        acc += logf((d + 1.0f) / (d + 1e-8f)) * W_dd[s * 20 + p];
    }
#pragma unroll
    for (int o = 32; o > 0; o >>= 1) acc += __shfl_down(acc, o);
    if (lane == 0) red[w] = acc;
    __syncthreads();
    if (tid == 0) dd_logit[b] = red[0] + red[1] + red[2] + red[3];
}

// ---------------------------------------------------------------------------
// Persistent LSTM: 32 blocks x 512 threads (8 waves). Block bn owns n' rows
// [64bn, 64bn+64) = j in [16bn, 16bn+16). Wave wv: bset = wv&3 (batch 16er),
// rbh = wv>>2 (row-block pair). Wh fragments live in REGISTERS (32 frags =
// 128 VGPRs, loaded once). No LDS in the step loop.
// h layout: elem(k,b) = (k>>4)*1024 + b*16 + (k&15); rotating 65 slots.
// Flags: one 128B line per block (flags[bn*32]), monotonic; wave0 polls,
// __syncthreads releases (also the compiler/memory barrier for plain h loads).
// ---------------------------------------------------------------------------
__global__ __launch_bounds__(512, 2) void k_lstm_persist(
    const ushort* __restrict__ xg,       // [s][b][n'] bf16
    const ushort* __restrict__ Whr,      // [n'=2048][k=512] bf16
    ushort* __restrict__ hbuf,           // 65 slots x 32768 (slot0 zeroed)
    int* __restrict__ flags,             // [32*32] pre-zeroed, line-padded
    const float* __restrict__ W_dec, const float* __restrict__ b_dec,
    const float* __restrict__ dd_logit, const float* __restrict__ b_dd,
    const float* __restrict__ g_logit, const float* __restrict__ b_gate,
    float* __restrict__ out)
{
    __shared__ float fred[8][64];
    const int tid = threadIdx.x;
    const int lane = tid & 63, wv = tid >> 6;
    const int quad = lane >> 4, l16 = lane & 15;
    const int bn = blockIdx.x;
    const int n0 = bn * 64;
    const int bset = wv & 3, rbh = wv >> 2;
    const int bg = bset * 16 + l16;          // this lane's batch row

    // Wh fragments -> registers (once). rb = rbh*2 + r.
    short8 wfrag[2][16];
#pragma unroll
    for (int r = 0; r < 2; ++r)
#pragma unroll
        for (int kc = 0; kc < 16; ++kc)
            wfrag[r][kc] = *(const short8*)(Whr +
                (size_t)(n0 + (rbh * 2 + r) * 16 + l16) * 512 + kc * 32 + quad * 8);

    float c0 = 0.f, c1 = 0.f;

    for (int s = 0; s < 64; ++s) {
        // xg prefetch (in flight during the poll)
        const ushort* xrow = xg + ((size_t)(s * 64 + bg)) * 2048 + n0;
        ushort4 xa = *(const ushort4*)(xrow + (rbh * 2 + 0) * 16 + quad * 4);
        ushort4 xb = *(const ushort4*)(xrow + (rbh * 2 + 1) * 16 + quad * 4);

        if (s > 0) {
            if (tid < 32) {
                while (__hip_atomic_load(&flags[tid * 32], __ATOMIC_RELAXED,
                                         __HIP_MEMORY_SCOPE_AGENT) < s) {}
            }
            __syncthreads();    // release + compiler/memory ordering for h loads
        }
        const ushort* hin = hbuf + (size_t)s * 32768;
        ushort* hout = hbuf + (size_t)(s + 1) * 32768;

        // h fragments: k = kc*32 + quad*8 + i  (contiguous 16B per lane)
        short8 hb[16];
#pragma unroll
        for (int kc = 0; kc < 16; ++kc)
            hb[kc] = *(const short8*)(hin + (size_t)(kc * 2 + (quad >> 1)) * 1024
                                          + bg * 16 + (quad & 1) * 8);
        f32x4 a0 = {}, a1 = {};
#pragma unroll
        for (int kc = 0; kc < 16; ++kc) {
            a0 = __builtin_amdgcn_mfma_f32_16x16x32_bf16(wfrag[0][kc], hb[kc], a0, 0, 0, 0);
            a1 = __builtin_amdgcn_mfma_f32_16x16x32_bf16(wfrag[1][kc], hb[kc], a1, 0, 0, 0);
        }
        // D: row = quad*4+gate -> j_loc = rb*4+quad, col = l16 (batch offset)
        {
            float gi = sigm(a0[0] + bf2f(xa.x));
            float gf = sigm(a0[1] + bf2f(xa.y));
            float go = sigm(a0[2] + bf2f(xa.z));
            float gg = tanh_fast(a0[3] + bf2f(xa.w));
            c0 = gf * c0 + gi * gg;
            __hip_atomic_store(&hout[bn * 1024 + bg * 16 + (rbh * 2 + 0) * 4 + quad],
                               f2bf(go * c0), __ATOMIC_RELAXED, __HIP_MEMORY_SCOPE_AGENT);
        }
        {
            float gi = sigm(a1[0] + bf2f(xb.x));
            float gf = sigm(a1[1] + bf2f(xb.y));
            float go = sigm(a1[2] + bf2f(xb.z));
            float gg = tanh_fast(a1[3] + bf2f(xb.w));
            c1 = gf * c1 + gi * gg;
            __hip_atomic_store(&hout[bn * 1024 + bg * 16 + (rbh * 2 + 1) * 4 + quad],
                               f2bf(go * c1), __ATOMIC_RELAXED, __HIP_MEMORY_SCOPE_AGENT);
        }
        __syncthreads();        // drains every wave's sc1 stores
        if (tid == 0)
            __hip_atomic_store(&flags[bn * 32], s + 1, __ATOMIC_RELAXED,
                               __HIP_MEMORY_SCOPE_AGENT);
    }

    // final head: h(64) in slot 64
    if (bn == 0) {
        if (tid < 32) {
            while (__hip_atomic_load(&flags[tid * 32], __ATOMIC_RELAXED,
                                     __HIP_MEMORY_SCOPE_AGENT) < 64) {}
        }
        __syncthreads();
        const ushort* hb64 = hbuf + (size_t)64 * 32768;
        int b = tid & 63, part = tid >> 6;   // 8 parts x 4 j-groups of 16
        float acc = 0.f;
#pragma unroll
        for (int g2 = 0; g2 < 4; ++g2) {
            int gg = part * 4 + g2;
            const ushort* hp = hb64 + gg * 1024 + b * 16;
            const float* wd = W_dec + gg * 16;
#pragma unroll
            for (int jj = 0; jj < 16; jj += 4) {
                ull u = *(const ull*)(hp + jj);
                acc += bf2f((ushort)u) * wd[jj]
                     + bf2f((ushort)(u >> 16)) * wd[jj + 1]
                     + bf2f((ushort)(u >> 32)) * wd[jj + 2]
                     + bf2f((ushort)(u >> 48)) * wd[jj + 3];
            }
        }
        fred[part][b] = acc;
        __syncthreads();
        if (tid < 64) {
            float a = 0.f;
#pragma unroll
            for (int p = 0; p < 8; ++p) a += fred[p][tid];
            float output = sigm(a + b_dec[0]);
            float gate   = sigm(g_logit[tid] * (1.0f / 64.f) + b_gate[0]);
            float ddp    = sigm(dd_logit[tid] + b_dd[0]);
            out[tid] = output * gate + ddp * (1.f - gate);
        }
    }
}

extern "C" void kernel_launch(void* const* d_in, const int* in_sizes, int n_in,
                              void* d_out, int out_size, void* d_ws, size_t ws_size,
                              hipStream_t stream) {
    const float* v_feat   = (const float*)d_in[0];
    const int*   category = (const int*)d_in[1];
    const float* W_enc    = (const float*)d_in[2];
    const float* b_enc    = (const float*)d_in[3];
    const float* Wx       = (const float*)d_in[4];
    const float* bx       = (const float*)d_in[5];
    const float* Wh       = (const float*)d_in[6];
    const float* bh       = (const float*)d_in[7];
    const float* cat_emb  = (const float*)d_in[8];
    const float* W_dec    = (const float*)d_in[9];
    const float* b_dec    = (const float*)d_in[10];
    const float* proto    = (const float*)d_in[11];
    const float* W_dd     = (const float*)d_in[12];
    const float* b_dd     = (const float*)d_in[13];
    const float* W_gate   = (const float*)d_in[14];
    const float* b_gate   = (const float*)d_in[15];
    float* out = (float*)d_out;

    char* ws = (char*)d_ws;
    ushort* xg       = (ushort*)(ws + 0);          // 16 MB bf16 [s][b][n']
    ushort* v_bf16   = (ushort*)(ws + 0);          // overlaps xg (k_dot before GEMM2)
    ushort* fuse     = (ushort*)(ws + 16777216);   // 4 MB bf16 [4096][512]
    ushort* Whr      = (ushort*)(ws + 20971520);   // 2 MB bf16 [2048][512] (n' rows)
    ushort* Wenc_t   = (ushort*)(ws + 23068672);   // 2 MB bf16 [512][2048]
    ushort* Wx_t     = (ushort*)(ws + 25165824);   // 2 MB bf16 [2048][512] (n' rows)
    ushort* proto_bf = (ushort*)(ws + 27262976);   // 128 KB [32][2048]
    float*  dots     = (float*)(ws + 27394048);    // 512 KB [4096][32]
    float*  n2       = (float*)(ws + 27918336);    // 16 KB
    float*  p2       = (float*)(ws + 27934720);    // 512 B
    float*  bxh      = (float*)(ws + 27935232);    // 8 KB
    int*    flags    = (int*)(ws + 27943424);      // 4 KB (32 x 128B lines)
    float*  dd_logit = (float*)(ws + 27947520);    // 256 B
    float*  g_logit  = (float*)(ws + 27947776);    // 256 B
    ushort* hbuf     = (ushort*)(ws + 27948032);   // 65 x 64 KB rotating h

    hipMemsetAsync(proto_bf, 0, 131072, stream);           // pad rows 20..31
    hipMemsetAsync(flags, 0, 4608, stream);                // flags + dd + g_logit
    hipMemsetAsync(hbuf, 0, 65536, stream);                // slot 0 = h(0) = 0

    k_prep<<<12337, 256, 0, stream>>>(v_feat, proto, bx, bh, W_enc, Wx, Wh, W_gate,
                                      v_bf16, proto_bf, bxh, Wenc_t, Wx_t, Whr,
                                      n2, g_logit, p2);

    k_gemm_mfma<<<dim3(4, 32), 256, 0, stream>>>(v_bf16, Wenc_t, 4096, 512, 2048,
                                                 b_enc, cat_emb, category, fuse, 0);
    k_dot<<<64, 256, 0, stream>>>(v_bf16, proto_bf, dots);
    k_dd<<<64, 256, 0, stream>>>(dots, n2, p2, W_dd, dd_logit);

    k_gemm_mfma<<<dim3(16, 32), 256, 0, stream>>>(fuse, Wx_t, 4096, 2048, 512,
                                                  bxh, nullptr, nullptr, xg, 1);

    k_lstm_persist<<<32, 512, 0, stream>>>(xg, Whr, hbuf, flags,
                                           W_dec, b_dec, dd_logit, b_dd,
                                           g_logit, b_gate, out);
}

// Round 9
// 423.131 us; speedup vs baseline: 1.2093x; 1.2093x over previous
//
#include <hip/hip_runtime.h>
#include <cstdint>
#include <cstddef>

// ---------------------------------------------------------------------------
// ASD_RNN round 9: persistent LSTM, 64 blocks x 512 thr, register-resident
// Wh (64 VGPR/wave), LDS-staged coalesced 8B h stores (no partial-line RMW),
// wave-autonomous relaxed polling.
// B=64, S=64, F_IN=2048, H=512, 4H=2048, P2=20.
// ---------------------------------------------------------------------------

typedef __attribute__((ext_vector_type(8))) short short8;
typedef __attribute__((ext_vector_type(4))) float f32x4;
typedef unsigned long long ull;

__device__ __forceinline__ ushort f2bf(float x) {
    uint32_t u = __float_as_uint(x);
    return (ushort)((u + 0x7FFF + ((u >> 16) & 1)) >> 16);   // RNE
}
__device__ __forceinline__ float bf2f(ushort u) {
    return __uint_as_float(((uint32_t)u) << 16);
}
__device__ __forceinline__ float sigm(float x) { return 1.f / (1.f + expf(-x)); }
__device__ __forceinline__ float tanh_fast(float x) { return 2.f / (1.f + expf(-2.f * x)) - 1.f; }

// ---------------------------------------------------------------------------
// k_prep: all independent pre-processing in one launch (block-range dispatch).
// ---------------------------------------------------------------------------
__global__ __launch_bounds__(256) void k_prep(
    const float* __restrict__ v_feat, const float* __restrict__ proto,
    const float* __restrict__ bx, const float* __restrict__ bh,
    const float* __restrict__ W_enc, const float* __restrict__ Wx,
    const float* __restrict__ Wh, const float* __restrict__ W_gate,
    ushort* __restrict__ v_bf16, ushort* __restrict__ proto_bf,
    float* __restrict__ bxh, ushort* __restrict__ Wenc_t,
    ushort* __restrict__ Wx_t, ushort* __restrict__ Whr,
    float* __restrict__ n2, float* __restrict__ g_logit, float* __restrict__ p2)
{
    __shared__ float ts[32][33];
    const int blk = blockIdx.x;
    const int tid = threadIdx.x;

    if (blk < 8192) {                               // v convert
        int i = blk * 256 + tid;
        float4 v = ((const float4*)v_feat)[i];
        ushort4 o;
        o.x = f2bf(v.x); o.y = f2bf(v.y); o.z = f2bf(v.z); o.w = f2bf(v.w);
        ((ushort4*)v_bf16)[i] = o;
    } else if (blk < 8232) {                        // proto convert
        int i = (blk - 8192) * 256 + tid;
        float4 v = ((const float4*)proto)[i];
        ushort4 o;
        o.x = f2bf(v.x); o.y = f2bf(v.y); o.z = f2bf(v.z); o.w = f2bf(v.w);
        ((ushort4*)proto_bf)[i] = o;
    } else if (blk < 8240) {                        // bias remap
        int n = (blk - 8232) * 256 + tid;
        int np = ((n & 511) << 2) | (n >> 9);
        bxh[np] = bx[n] + bh[n];
    } else if (blk < 11312) {                       // the three transposes
        const float* in;
        ushort* outp;
        int R, C, remap, t;
        if (blk < 9264)       { in = W_enc; outp = Wenc_t; R = 2048; C = 512;  remap = 0; t = blk - 8240; }
        else if (blk < 10288) { in = Wx;    outp = Wx_t;   R = 512;  C = 2048; remap = 1; t = blk - 9264; }
        else                  { in = Wh;    outp = Whr;    R = 512;  C = 2048; remap = 1; t = blk - 10288; }
        int tpr = C / 32;
        int cx = t % tpr, cy = t / tpr;
        int r0 = cy * 32, c0 = cx * 32;
        int rr = tid >> 3, cc = (tid & 7) * 4;
        float4 v = *(const float4*)(in + (size_t)(r0 + rr) * C + c0 + cc);
        ts[rr][cc + 0] = v.x; ts[rr][cc + 1] = v.y; ts[rr][cc + 2] = v.z; ts[rr][cc + 3] = v.w;
        __syncthreads();
        ushort4 o;
        o.x = f2bf(ts[cc + 0][rr]);
        o.y = f2bf(ts[cc + 1][rr]);
        o.z = f2bf(ts[cc + 2][rr]);
        o.w = f2bf(ts[cc + 3][rr]);
        int n = c0 + rr;
        int np = remap ? (((n & 511) << 2) | (n >> 9)) : n;
        *(ushort4*)(outp + (size_t)np * R + r0 + cc) = o;
    } else if (blk < 12336) {                       // rowstats
        const int lane = tid & 63, w = tid >> 6;
        const int bs = (blk - 11312) * 4 + w;
        const float* vr = v_feat + (size_t)bs * 2048;
        float a = 0.f, g = 0.f;
#pragma unroll
        for (int i = 0; i < 8; ++i) {
            float4 x = ((const float4*)vr)[i * 64 + lane];
            float4 wg = ((const float4*)W_gate)[i * 64 + lane];
            a += x.x * x.x + x.y * x.y + x.z * x.z + x.w * x.w;
            g += x.x * wg.x + x.y * wg.y + x.z * wg.z + x.w * wg.w;
        }
#pragma unroll
        for (int o = 32; o > 0; o >>= 1) { a += __shfl_down(a, o); g += __shfl_down(g, o); }
        if (lane == 0) {
            n2[bs] = a;
            atomicAdd(&g_logit[bs >> 6], g);
        }
    } else {                                        // p2 (one block)
        const int lane = tid & 63, w = tid >> 6;
        for (int p = w; p < 20; p += 4) {
            const float* pr = proto + (size_t)p * 2048;
            float a = 0.f;
#pragma unroll
            for (int i = 0; i < 8; ++i) {
                float4 x = ((const float4*)pr)[i * 64 + lane];
                a += x.x * x.x + x.y * x.y + x.z * x.z + x.w * x.w;
            }
#pragma unroll
            for (int o = 32; o > 0; o >>= 1) a += __shfl_down(a, o);
            if (lane == 0) p2[p] = a;
        }
    }
}

// bf16 MFMA GEMM: C[M,N] = A[M,K] @ Bt[N,K]^T. 128x128 tile, 4 waves of 64x64.
__global__ __launch_bounds__(256) void k_gemm_mfma(
    const ushort* __restrict__ A, const ushort* __restrict__ Bt,
    int M, int N, int K,
    const float* __restrict__ bias0,
    const float* __restrict__ cat_emb, const int* __restrict__ category,
    void* __restrict__ Cout, int mode)
{
    __shared__ ushort As[128][40];
    __shared__ ushort Bs[128][40];
    const int tid = threadIdx.x;
    const int lane = tid & 63, w = tid >> 6;
    const int quad = lane >> 4, l16 = lane & 15;
    const int m0 = blockIdx.y * 128, n0 = blockIdx.x * 128;
    const int wm = (w & 1) * 64, wn = (w >> 1) * 64;

    f32x4 acc[4][4] = {};
    const int lr = tid >> 2;
    const int lc = (tid & 3) * 8;

    for (int k0 = 0; k0 < K; k0 += 32) {
        uint4 a0 = *(const uint4*)(A + (size_t)(m0 + lr) * K + k0 + lc);
        uint4 a1 = *(const uint4*)(A + (size_t)(m0 + 64 + lr) * K + k0 + lc);
        uint4 b0 = *(const uint4*)(Bt + (size_t)(n0 + lr) * K + k0 + lc);
        uint4 b1 = *(const uint4*)(Bt + (size_t)(n0 + 64 + lr) * K + k0 + lc);
        __syncthreads();
        *(uint4*)&As[lr][lc] = a0;
        *(uint4*)&As[64 + lr][lc] = a1;
        *(uint4*)&Bs[lr][lc] = b0;
        *(uint4*)&Bs[64 + lr][lc] = b1;
        __syncthreads();
        short8 af[4], bf[4];
#pragma unroll
        for (int i = 0; i < 4; ++i) af[i] = *(const short8*)&As[wm + i * 16 + l16][quad * 8];
#pragma unroll
        for (int j = 0; j < 4; ++j) bf[j] = *(const short8*)&Bs[wn + j * 16 + l16][quad * 8];
#pragma unroll
        for (int i = 0; i < 4; ++i)
#pragma unroll
            for (int j = 0; j < 4; ++j)
                acc[i][j] = __builtin_amdgcn_mfma_f32_16x16x32_bf16(af[i], bf[j], acc[i][j], 0, 0, 0);
    }

    if (mode == 0) {
        ushort* C = (ushort*)Cout;
#pragma unroll
        for (int i = 0; i < 4; ++i) {
            int mbase = m0 + wm + i * 16 + quad * 4;
#pragma unroll
            for (int r = 0; r < 4; ++r) {
                int m = mbase + r;
                const float* ce = cat_emb + category[m >> 6] * 512;
#pragma unroll
                for (int j = 0; j < 4; ++j) {
                    int n = n0 + wn + j * 16 + l16;
                    float v = fmaxf(acc[i][j][r] + bias0[n], 0.f) + ce[n];
                    C[(size_t)m * 512 + n] = f2bf(v);
                }
            }
        }
    } else {
        ushort* C = (ushort*)Cout;
        float bb[4];
#pragma unroll
        for (int j = 0; j < 4; ++j) bb[j] = bias0[n0 + wn + j * 16 + l16];
#pragma unroll
        for (int i = 0; i < 4; ++i) {
            int mbase = m0 + wm + i * 16 + quad * 4;
#pragma unroll
            for (int r = 0; r < 4; ++r) {
                int m = mbase + r;
                int s = m & 63, b = m >> 6;
                ushort* crow = C + ((size_t)(s * 64 + b)) * 2048;
#pragma unroll
                for (int j = 0; j < 4; ++j)
                    crow[n0 + wn + j * 16 + l16] = f2bf(acc[i][j][r] + bb[j]);
            }
        }
    }
}

// dots[bs][p] = v_bf16[bs][:] . proto_bf[p][:] (proto padded to 32 rows)
__global__ __launch_bounds__(256) void k_dot(const ushort* __restrict__ v_bf,
                                             const ushort* __restrict__ proto_bf,
                                             float* __restrict__ dots)
{
    const int tid = threadIdx.x;
    const int lane = tid & 63, w = tid >> 6;
    const int quad = lane >> 4, l16 = lane & 15;
    const int r0 = blockIdx.x * 64 + w * 16;

    f32x4 acc[2] = {};
    const ushort* arow = v_bf + (size_t)(r0 + l16) * 2048 + quad * 8;
    const ushort* b0p = proto_bf + (size_t)l16 * 2048 + quad * 8;
    const ushort* b1p = proto_bf + (size_t)(16 + l16) * 2048 + quad * 8;
#pragma unroll 8
    for (int kk = 0; kk < 64; ++kk) {
        short8 af = *(const short8*)(arow + kk * 32);
        short8 bf0 = *(const short8*)(b0p + kk * 32);
        short8 bf1 = *(const short8*)(b1p + kk * 32);
        acc[0] = __builtin_amdgcn_mfma_f32_16x16x32_bf16(af, bf0, acc[0], 0, 0, 0);
        acc[1] = __builtin_amdgcn_mfma_f32_16x16x32_bf16(af, bf1, acc[1], 0, 0, 0);
    }
#pragma unroll
    for (int t = 0; t < 2; ++t)
#pragma unroll
        for (int r = 0; r < 4; ++r)
            dots[(size_t)(r0 + quad * 4 + r) * 32 + t * 16 + l16] = acc[t][r];
}

// dd_logit[b] = sum_{s,p} log((d+1)/(d+1e-8)) * W_dd[s*20+p]. grid 64.
__global__ __launch_bounds__(256) void k_dd(const float* __restrict__ dots,
                                            const float* __restrict__ n2,
                                            const float* __restrict__ p2,
                                            const float* __restrict__ W_dd,
                                            float* __restrict__ dd_logit)
{
    __shared__ float red[4];
    const int b = blockIdx.x;
    const int tid = threadIdx.x, lane = tid & 63, w = tid >> 6;
    float acc = 0.f;
    for (int u = tid; u < 1280; u += 256) {
        int s = u / 20, p = u - s * 20;
        int bs = b * 64 + s;
        float d = n2[bs] - 2.f * dots[(size_t)bs * 32 + p] + p2[p];
        acc += logf((d + 1.0f) / (d + 1e-8f)) * W_dd[s * 20 + p];
    }
#pragma unroll
    for (int o = 32; o > 0; o >>= 1) acc += __shfl_down(acc, o);
    if (lane == 0) red[w] = acc;
    __syncthreads();
    if (tid == 0) dd_logit[b] = red[0] + red[1] + red[2] + red[3];
}

// ---------------------------------------------------------------------------
// Persistent LSTM: 64 blocks x 512 threads (8 waves). Block bn owns n' rows
// [32bn, 32bn+32) = j in [8bn, 8bn+8). Wave wv: bset = wv&3, rb = wv>>2.
// Wh fragments in REGISTERS: wfrag[16] = 64 VGPRs (fits; verify VGPR>=160).
// h layout: elem(k,b) = (k>>3)*512 + b*8 + (k&7); block slice = 1 KB contig.
// h publication: gates -> LDS tile (1 KB) -> 128 x 8B coalesced sc1 stores
// (full 128B lines, no RMW). Flags: one 128B line per block, monotonic;
// every lane polls flags[lane] (wave-autonomous), asm memory barrier pins
// load order; vmcnt drain at the post-store __syncthreads orders flag store.
// ---------------------------------------------------------------------------
__global__ __launch_bounds__(512, 2) void k_lstm_persist(
    const ushort* __restrict__ xg,       // [s][b][n'] bf16
    const ushort* __restrict__ Whr,      // [n'=2048][k=512] bf16
    ushort* __restrict__ hbuf,           // 65 slots x 32768 (slot0 zeroed)
    int* __restrict__ flags,             // [64*32] pre-zeroed, line-padded
    const float* __restrict__ W_dec, const float* __restrict__ b_dec,
    const float* __restrict__ dd_logit, const float* __restrict__ b_dd,
    const float* __restrict__ g_logit, const float* __restrict__ b_gate,
    float* __restrict__ out)
{
    __shared__ ushort hstage[512];       // [b][j_loc] = b*8 + j_loc
    __shared__ float fred[8][64];
    const int tid = threadIdx.x;
    const int lane = tid & 63, wv = tid >> 6;
    const int quad = lane >> 4, l16 = lane & 15;
    const int bn = blockIdx.x;
    const int n0 = bn * 32;
    const int bset = wv & 3, rb = wv >> 2;      // rb in {0,1}
    const int bg = bset * 16 + l16;             // this lane's batch row
    const int jl = rb * 4 + quad;               // j_loc in [0,8)

    // Wh fragments -> registers (once): rows n0 + rb*16 + l16, k chunks of 32
    short8 wfrag[16];
#pragma unroll
    for (int kc = 0; kc < 16; ++kc)
        wfrag[kc] = *(const short8*)(Whr +
            (size_t)(n0 + rb * 16 + l16) * 512 + kc * 32 + quad * 8);

    float c = 0.f;

    for (int s = 0; s < 64; ++s) {
        // xg prefetch (in flight during the poll)
        const ushort* xrow = xg + ((size_t)(s * 64 + bg)) * 2048 + n0;
        ushort4 xa = *(const ushort4*)(xrow + rb * 16 + quad * 4);

        if (s > 0) {
            const int* f = flags + lane * 32;   // lane i watches block i
            while (__hip_atomic_load(f, __ATOMIC_RELAXED,
                                     __HIP_MEMORY_SCOPE_AGENT) < s) {}
            asm volatile("" ::: "memory");      // pin h loads after the poll
        }
        const ushort* hin = hbuf + (size_t)s * 32768;
        ushort* hout = hbuf + (size_t)(s + 1) * 32768;

        // h fragments: k = kc*32 + quad*8 + i  -> elem (kc*4+quad)*512 + bg*8 + i
        short8 hb[16];
#pragma unroll
        for (int kc = 0; kc < 16; ++kc)
            hb[kc] = *(const short8*)(hin + (size_t)(kc * 4 + quad) * 512 + bg * 8);
        f32x4 a0 = {};
#pragma unroll
        for (int kc = 0; kc < 16; ++kc)
            a0 = __builtin_amdgcn_mfma_f32_16x16x32_bf16(wfrag[kc], hb[kc], a0, 0, 0, 0);

        // D: n'-offset = quad*4 + reg -> gate = reg, j_loc = rb*4 + quad
        float gi = sigm(a0[0] + bf2f(xa.x));
        float gf = sigm(a0[1] + bf2f(xa.y));
        float go = sigm(a0[2] + bf2f(xa.z));
        float gg = tanh_fast(a0[3] + bf2f(xa.w));
        c = gf * c + gi * gg;
        hstage[bg * 8 + jl] = f2bf(go * c);      // no tanh on c (matches ref)

        __syncthreads();                         // hstage complete
        if (tid < 128)
            __hip_atomic_store((ull*)(hout + bn * 512) + tid,
                               ((const ull*)hstage)[tid],
                               __ATOMIC_RELAXED, __HIP_MEMORY_SCOPE_AGENT);
        __syncthreads();                         // drains vmcnt of the stores
        if (tid == 0)
            __hip_atomic_store(&flags[bn * 32], s + 1, __ATOMIC_RELAXED,
                               __HIP_MEMORY_SCOPE_AGENT);
    }

    // final head: h(64) in slot 64
    if (bn == 0) {
        if (tid < 64) {
            while (__hip_atomic_load(&flags[tid * 32], __ATOMIC_RELAXED,
                                     __HIP_MEMORY_SCOPE_AGENT) < 64) {}
        }
        __syncthreads();
        asm volatile("" ::: "memory");
        const ushort* hb64 = hbuf + (size_t)64 * 32768;
        int b = tid & 63, part = tid >> 6;       // part owns j in [part*64, +64)
        float acc = 0.f;
#pragma unroll
        for (int g8 = 0; g8 < 8; ++g8) {
            int grp = part * 8 + g8;             // k-group of 8
            const ushort* hp = hb64 + grp * 512 + b * 8;
            const float* wd = W_dec + grp * 8;
#pragma unroll
            for (int half = 0; half < 2; ++half) {
                ull u = *(const ull*)(hp + half * 4);
                acc += bf2f((ushort)u) * wd[half * 4]
                     + bf2f((ushort)(u >> 16)) * wd[half * 4 + 1]
                     + bf2f((ushort)(u >> 32)) * wd[half * 4 + 2]
                     + bf2f((ushort)(u >> 48)) * wd[half * 4 + 3];
            }
        }
        fred[part][b] = acc;
        __syncthreads();
        if (tid < 64) {
            float a = 0.f;
#pragma unroll
            for (int p = 0; p < 8; ++p) a += fred[p][tid];
            float output = sigm(a + b_dec[0]);
            float gate   = sigm(g_logit[tid] * (1.0f / 64.f) + b_gate[0]);
            float ddp    = sigm(dd_logit[tid] + b_dd[0]);
            out[tid] = output * gate + ddp * (1.f - gate);
        }
    }
}

extern "C" void kernel_launch(void* const* d_in, const int* in_sizes, int n_in,
                              void* d_out, int out_size, void* d_ws, size_t ws_size,
                              hipStream_t stream) {
    const float* v_feat   = (const float*)d_in[0];
    const int*   category = (const int*)d_in[1];
    const float* W_enc    = (const float*)d_in[2];
    const float* b_enc    = (const float*)d_in[3];
    const float* Wx       = (const float*)d_in[4];
    const float* bx       = (const float*)d_in[5];
    const float* Wh       = (const float*)d_in[6];
    const float* bh       = (const float*)d_in[7];
    const float* cat_emb  = (const float*)d_in[8];
    const float* W_dec    = (const float*)d_in[9];
    const float* b_dec    = (const float*)d_in[10];
    const float* proto    = (const float*)d_in[11];
    const float* W_dd     = (const float*)d_in[12];
    const float* b_dd     = (const float*)d_in[13];
    const float* W_gate   = (const float*)d_in[14];
    const float* b_gate   = (const float*)d_in[15];
    float* out = (float*)d_out;

    char* ws = (char*)d_ws;
    ushort* xg       = (ushort*)(ws + 0);          // 16 MB bf16 [s][b][n']
    ushort* v_bf16   = (ushort*)(ws + 0);          // overlaps xg (k_dot before GEMM2)
    ushort* fuse     = (ushort*)(ws + 16777216);   // 4 MB bf16 [4096][512]
    ushort* Whr      = (ushort*)(ws + 20971520);   // 2 MB bf16 [2048][512] (n' rows)
    ushort* Wenc_t   = (ushort*)(ws + 23068672);   // 2 MB bf16 [512][2048]
    ushort* Wx_t     = (ushort*)(ws + 25165824);   // 2 MB bf16 [2048][512] (n' rows)
    ushort* proto_bf = (ushort*)(ws + 27262976);   // 128 KB [32][2048]
    float*  dots     = (float*)(ws + 27394048);    // 512 KB [4096][32]
    float*  n2       = (float*)(ws + 27918336);    // 16 KB
    float*  p2       = (float*)(ws + 27934720);    // 512 B
    float*  bxh      = (float*)(ws + 27935232);    // 8 KB
    int*    flags    = (int*)(ws + 27943424);      // 8 KB (64 x 128B lines)
    float*  dd_logit = (float*)(ws + 27951616);    // 256 B
    float*  g_logit  = (float*)(ws + 27951872);    // 256 B
    ushort* hbuf     = (ushort*)(ws + 27952128);   // 65 x 64 KB rotating h

    hipMemsetAsync(proto_bf, 0, 131072, stream);   // pad rows 20..31
    hipMemsetAsync(flags, 0, 8704, stream);        // flags + dd_logit + g_logit
    hipMemsetAsync(hbuf, 0, 65536, stream);        // slot 0 = h(0) = 0

    k_prep<<<12337, 256, 0, stream>>>(v_feat, proto, bx, bh, W_enc, Wx, Wh, W_gate,
                                      v_bf16, proto_bf, bxh, Wenc_t, Wx_t, Whr,
                                      n2, g_logit, p2);

    k_gemm_mfma<<<dim3(4, 32), 256, 0, stream>>>(v_bf16, Wenc_t, 4096, 512, 2048,
                                                 b_enc, cat_emb, category, fuse, 0);
    k_dot<<<64, 256, 0, stream>>>(v_bf16, proto_bf, dots);
    k_dd<<<64, 256, 0, stream>>>(dots, n2, p2, W_dd, dd_logit);

    k_gemm_mfma<<<dim3(16, 32), 256, 0, stream>>>(fuse, Wx_t, 4096, 2048, 512,
                                                  bxh, nullptr, nullptr, xg, 1);

    k_lstm_persist<<<64, 512, 0, stream>>>(xg, Whr, hbuf, flags,
                                           W_dec, b_dec, dd_logit, b_dd,
                                           g_logit, b_gate, out);
}

// Round 10
// 390.728 us; speedup vs baseline: 1.3096x; 1.0829x over previous
//
#include <hip/hip_runtime.h>
#include <cstdint>
#include <cstddef>

// ---------------------------------------------------------------------------
// ASD_RNN round 10: LSTM with wave0-only flag polling (poll-contention fix);
// memset-free pipeline (zeroing folded into k_prep; atomic-free rowstats).
// B=64, S=64, F_IN=2048, H=512, 4H=2048, P2=20.
// ---------------------------------------------------------------------------

typedef __attribute__((ext_vector_type(8))) short short8;
typedef __attribute__((ext_vector_type(4))) float f32x4;
typedef unsigned long long ull;

__device__ __forceinline__ ushort f2bf(float x) {
    uint32_t u = __float_as_uint(x);
    return (ushort)((u + 0x7FFF + ((u >> 16) & 1)) >> 16);   // RNE
}
__device__ __forceinline__ float bf2f(ushort u) {
    return __uint_as_float(((uint32_t)u) << 16);
}
__device__ __forceinline__ float sigm(float x) { return 1.f / (1.f + expf(-x)); }
__device__ __forceinline__ float tanh_fast(float x) { return 2.f / (1.f + expf(-2.f * x)) - 1.f; }

// ---------------------------------------------------------------------------
// k_prep: ALL pre-processing + workspace zeroing in one launch.
//   [0,8192)       v_feat fp32 -> bf16
//   [8192,8232)    proto fp32 -> bf16
//   [8232,8244)    proto_bf zero rows 20..31
//   [8244,8252)    bxh[n'] = bx+bh (remapped)
//   [8252,9276)    W_enc^T -> Wenc_t
//   [9276,10300)   Wx^T -> Wx_t (n' remap)
//   [10300,11324)  Wh^T -> Whr (n' remap)
//   [11324,12348)  rowstats: n2[bs], gpart[bs] (no atomics)
//   [12348]        p2
//   [12349,12381)  hbuf slot 0 zero (64 KB)
//   [12381]        flags zero (8 KB)
// ---------------------------------------------------------------------------
__global__ __launch_bounds__(256) void k_prep(
    const float* __restrict__ v_feat, const float* __restrict__ proto,
    const float* __restrict__ bx, const float* __restrict__ bh,
    const float* __restrict__ W_enc, const float* __restrict__ Wx,
    const float* __restrict__ Wh, const float* __restrict__ W_gate,
    ushort* __restrict__ v_bf16, ushort* __restrict__ proto_bf,
    float* __restrict__ bxh, ushort* __restrict__ Wenc_t,
    ushort* __restrict__ Wx_t, ushort* __restrict__ Whr,
    float* __restrict__ n2, float* __restrict__ gpart, float* __restrict__ p2,
    ushort* __restrict__ hbuf, int* __restrict__ flags)
{
    __shared__ float ts[32][33];
    const int blk = blockIdx.x;
    const int tid = threadIdx.x;

    if (blk < 8192) {                               // v convert
        int i = blk * 256 + tid;
        float4 v = ((const float4*)v_feat)[i];
        ushort4 o;
        o.x = f2bf(v.x); o.y = f2bf(v.y); o.z = f2bf(v.z); o.w = f2bf(v.w);
        ((ushort4*)v_bf16)[i] = o;
    } else if (blk < 8232) {                        // proto convert
        int i = (blk - 8192) * 256 + tid;
        float4 v = ((const float4*)proto)[i];
        ushort4 o;
        o.x = f2bf(v.x); o.y = f2bf(v.y); o.z = f2bf(v.z); o.w = f2bf(v.w);
        ((ushort4*)proto_bf)[i] = o;
    } else if (blk < 8244) {                        // proto pad rows 20..31
        int row = 20 + (blk - 8232);
        ushort4 z = {0, 0, 0, 0};
        ((ushort4*)(proto_bf + (size_t)row * 2048))[tid * 2] = z;
        ((ushort4*)(proto_bf + (size_t)row * 2048))[tid * 2 + 1] = z;
    } else if (blk < 8252) {                        // bias remap
        int n = (blk - 8244) * 256 + tid;
        int np = ((n & 511) << 2) | (n >> 9);
        bxh[np] = bx[n] + bh[n];
    } else if (blk < 11324) {                       // transposes
        const float* in;
        ushort* outp;
        int R, C, remap, t;
        if (blk < 9276)       { in = W_enc; outp = Wenc_t; R = 2048; C = 512;  remap = 0; t = blk - 8252; }
        else if (blk < 10300) { in = Wx;    outp = Wx_t;   R = 512;  C = 2048; remap = 1; t = blk - 9276; }
        else                  { in = Wh;    outp = Whr;    R = 512;  C = 2048; remap = 1; t = blk - 10300; }
        int tpr = C / 32;
        int cx = t % tpr, cy = t / tpr;
        int r0 = cy * 32, c0 = cx * 32;
        int rr = tid >> 3, cc = (tid & 7) * 4;
        float4 v = *(const float4*)(in + (size_t)(r0 + rr) * C + c0 + cc);
        ts[rr][cc + 0] = v.x; ts[rr][cc + 1] = v.y; ts[rr][cc + 2] = v.z; ts[rr][cc + 3] = v.w;
        __syncthreads();
        ushort4 o;
        o.x = f2bf(ts[cc + 0][rr]);
        o.y = f2bf(ts[cc + 1][rr]);
        o.z = f2bf(ts[cc + 2][rr]);
        o.w = f2bf(ts[cc + 3][rr]);
        int n = c0 + rr;
        int np = remap ? (((n & 511) << 2) | (n >> 9)) : n;
        *(ushort4*)(outp + (size_t)np * R + r0 + cc) = o;
    } else if (blk < 12348) {                       // rowstats (atomic-free)
        const int lane = tid & 63, w = tid >> 6;
        const int bs = (blk - 11324) * 4 + w;
        const float* vr = v_feat + (size_t)bs * 2048;
        float a = 0.f, g = 0.f;
#pragma unroll
        for (int i = 0; i < 8; ++i) {
            float4 x = ((const float4*)vr)[i * 64 + lane];
            float4 wg = ((const float4*)W_gate)[i * 64 + lane];
            a += x.x * x.x + x.y * x.y + x.z * x.z + x.w * x.w;
            g += x.x * wg.x + x.y * wg.y + x.z * wg.z + x.w * wg.w;
        }
#pragma unroll
        for (int o = 32; o > 0; o >>= 1) { a += __shfl_down(a, o); g += __shfl_down(g, o); }
        if (lane == 0) {
            n2[bs] = a;
            gpart[bs] = g;
        }
    } else if (blk == 12348) {                      // p2
        const int lane = tid & 63, w = tid >> 6;
        for (int p = w; p < 20; p += 4) {
            const float* pr = proto + (size_t)p * 2048;
            float a = 0.f;
#pragma unroll
            for (int i = 0; i < 8; ++i) {
                float4 x = ((const float4*)pr)[i * 64 + lane];
                a += x.x * x.x + x.y * x.y + x.z * x.z + x.w * x.w;
            }
#pragma unroll
            for (int o = 32; o > 0; o >>= 1) a += __shfl_down(a, o);
            if (lane == 0) p2[p] = a;
        }
    } else if (blk < 12381) {                       // hbuf slot 0 zero
        ((ull*)hbuf)[(blk - 12349) * 256 + tid] = 0ULL;
    } else {                                        // flags zero (2048 ints)
        for (int i = tid; i < 2048; i += 256) flags[i] = 0;
    }
}

// bf16 MFMA GEMM: C[M,N] = A[M,K] @ Bt[N,K]^T. 128x128 tile, 4 waves of 64x64.
__global__ __launch_bounds__(256) void k_gemm_mfma(
    const ushort* __restrict__ A, const ushort* __restrict__ Bt,
    int M, int N, int K,
    const float* __restrict__ bias0,
    const float* __restrict__ cat_emb, const int* __restrict__ category,
    void* __restrict__ Cout, int mode)
{
    __shared__ ushort As[128][40];
    __shared__ ushort Bs[128][40];
    const int tid = threadIdx.x;
    const int lane = tid & 63, w = tid >> 6;
    const int quad = lane >> 4, l16 = lane & 15;
    const int m0 = blockIdx.y * 128, n0 = blockIdx.x * 128;
    const int wm = (w & 1) * 64, wn = (w >> 1) * 64;

    f32x4 acc[4][4] = {};
    const int lr = tid >> 2;
    const int lc = (tid & 3) * 8;

    for (int k0 = 0; k0 < K; k0 += 32) {
        uint4 a0 = *(const uint4*)(A + (size_t)(m0 + lr) * K + k0 + lc);
        uint4 a1 = *(const uint4*)(A + (size_t)(m0 + 64 + lr) * K + k0 + lc);
        uint4 b0 = *(const uint4*)(Bt + (size_t)(n0 + lr) * K + k0 + lc);
        uint4 b1 = *(const uint4*)(Bt + (size_t)(n0 + 64 + lr) * K + k0 + lc);
        __syncthreads();
        *(uint4*)&As[lr][lc] = a0;
        *(uint4*)&As[64 + lr][lc] = a1;
        *(uint4*)&Bs[lr][lc] = b0;
        *(uint4*)&Bs[64 + lr][lc] = b1;
        __syncthreads();
        short8 af[4], bf[4];
#pragma unroll
        for (int i = 0; i < 4; ++i) af[i] = *(const short8*)&As[wm + i * 16 + l16][quad * 8];
#pragma unroll
        for (int j = 0; j < 4; ++j) bf[j] = *(const short8*)&Bs[wn + j * 16 + l16][quad * 8];
#pragma unroll
        for (int i = 0; i < 4; ++i)
#pragma unroll
            for (int j = 0; j < 4; ++j)
                acc[i][j] = __builtin_amdgcn_mfma_f32_16x16x32_bf16(af[i], bf[j], acc[i][j], 0, 0, 0);
    }

    if (mode == 0) {
        ushort* C = (ushort*)Cout;
#pragma unroll
        for (int i = 0; i < 4; ++i) {
            int mbase = m0 + wm + i * 16 + quad * 4;
#pragma unroll
            for (int r = 0; r < 4; ++r) {
                int m = mbase + r;
                const float* ce = cat_emb + category[m >> 6] * 512;
#pragma unroll
                for (int j = 0; j < 4; ++j) {
                    int n = n0 + wn + j * 16 + l16;
                    float v = fmaxf(acc[i][j][r] + bias0[n], 0.f) + ce[n];
                    C[(size_t)m * 512 + n] = f2bf(v);
                }
            }
        }
    } else {
        ushort* C = (ushort*)Cout;
        float bb[4];
#pragma unroll
        for (int j = 0; j < 4; ++j) bb[j] = bias0[n0 + wn + j * 16 + l16];
#pragma unroll
        for (int i = 0; i < 4; ++i) {
            int mbase = m0 + wm + i * 16 + quad * 4;
#pragma unroll
            for (int r = 0; r < 4; ++r) {
                int m = mbase + r;
                int s = m & 63, b = m >> 6;
                ushort* crow = C + ((size_t)(s * 64 + b)) * 2048;
#pragma unroll
                for (int j = 0; j < 4; ++j)
                    crow[n0 + wn + j * 16 + l16] = f2bf(acc[i][j][r] + bb[j]);
            }
        }
    }
}

// dots[bs][p] = v_bf16[bs][:] . proto_bf[p][:] (proto padded to 32 rows)
__global__ __launch_bounds__(256) void k_dot(const ushort* __restrict__ v_bf,
                                             const ushort* __restrict__ proto_bf,
                                             float* __restrict__ dots)
{
    const int tid = threadIdx.x;
    const int lane = tid & 63, w = tid >> 6;
    const int quad = lane >> 4, l16 = lane & 15;
    const int r0 = blockIdx.x * 64 + w * 16;

    f32x4 acc[2] = {};
    const ushort* arow = v_bf + (size_t)(r0 + l16) * 2048 + quad * 8;
    const ushort* b0p = proto_bf + (size_t)l16 * 2048 + quad * 8;
    const ushort* b1p = proto_bf + (size_t)(16 + l16) * 2048 + quad * 8;
#pragma unroll 8
    for (int kk = 0; kk < 64; ++kk) {
        short8 af = *(const short8*)(arow + kk * 32);
        short8 bf0 = *(const short8*)(b0p + kk * 32);
        short8 bf1 = *(const short8*)(b1p + kk * 32);
        acc[0] = __builtin_amdgcn_mfma_f32_16x16x32_bf16(af, bf0, acc[0], 0, 0, 0);
        acc[1] = __builtin_amdgcn_mfma_f32_16x16x32_bf16(af, bf1, acc[1], 0, 0, 0);
    }
#pragma unroll
    for (int t = 0; t < 2; ++t)
#pragma unroll
        for (int r = 0; r < 4; ++r)
            dots[(size_t)(r0 + quad * 4 + r) * 32 + t * 16 + l16] = acc[t][r];
}

// dd_logit[b] = sum_{s,p} log((d+1)/(d+1e-8)) * W_dd[s*20+p];
// g_logit[b] = sum_s gpart[b*64+s]. grid 64.
__global__ __launch_bounds__(256) void k_dd(const float* __restrict__ dots,
                                            const float* __restrict__ n2,
                                            const float* __restrict__ p2,
                                            const float* __restrict__ W_dd,
                                            const float* __restrict__ gpart,
                                            float* __restrict__ dd_logit,
                                            float* __restrict__ g_logit)
{
    __shared__ float red[4];
    const int b = blockIdx.x;
    const int tid = threadIdx.x, lane = tid & 63, w = tid >> 6;

    if (tid < 64) {                  // g_logit reduction (wave 0)
        float gp = gpart[b * 64 + tid];
#pragma unroll
        for (int o = 32; o > 0; o >>= 1) gp += __shfl_down(gp, o);
        if (tid == 0) g_logit[b] = gp;
    }

    float acc = 0.f;
    for (int u = tid; u < 1280; u += 256) {
        int s = u / 20, p = u - s * 20;
        int bs = b * 64 + s;
        float d = n2[bs] - 2.f * dots[(size_t)bs * 32 + p] + p2[p];
        acc += logf((d + 1.0f) / (d + 1e-8f)) * W_dd[s * 20 + p];
    }
#pragma unroll
    for (int o = 32; o > 0; o >>= 1) acc += __shfl_down(acc, o);
    if (lane == 0) red[w] = acc;
    __syncthreads();
    if (tid == 0) dd_logit[b] = red[0] + red[1] + red[2] + red[3];
}

// ---------------------------------------------------------------------------
// Persistent LSTM: 64 blocks x 512 threads. Identical to round 9 except the
// wait: ONLY wave 0 polls (lane i -> flag i; 1 poller/flag/block), then
// __syncthreads releases waves 1..7 — cuts LLC flag-line readers 8x.
// ---------------------------------------------------------------------------
__global__ __launch_bounds__(512, 2) void k_lstm_persist(
    const ushort* __restrict__ xg,       // [s][b][n'] bf16
    const ushort* __restrict__ Whr,      // [n'=2048][k=512] bf16
    ushort* __restrict__ hbuf,           // 65 slots x 32768 (slot0 zeroed)
    int* __restrict__ flags,             // [64*32] zeroed, line-padded
    const float* __restrict__ W_dec, const float* __restrict__ b_dec,
    const float* __restrict__ dd_logit, const float* __restrict__ b_dd,
    const float* __restrict__ g_logit, const float* __restrict__ b_gate,
    float* __restrict__ out)
{
    __shared__ ushort hstage[512];       // [b][j_loc]
    __shared__ float fred[8][64];
    const int tid = threadIdx.x;
    const int lane = tid & 63, wv = tid >> 6;
    const int quad = lane >> 4, l16 = lane & 15;
    const int bn = blockIdx.x;
    const int n0 = bn * 32;
    const int bset = wv & 3, rb = wv >> 2;
    const int bg = bset * 16 + l16;
    const int jl = rb * 4 + quad;

    short8 wfrag[16];
#pragma unroll
    for (int kc = 0; kc < 16; ++kc)
        wfrag[kc] = *(const short8*)(Whr +
            (size_t)(n0 + rb * 16 + l16) * 512 + kc * 32 + quad * 8);

    float c = 0.f;

    for (int s = 0; s < 64; ++s) {
        const ushort* xrow = xg + ((size_t)(s * 64 + bg)) * 2048 + n0;
        ushort4 xa = *(const ushort4*)(xrow + rb * 16 + quad * 4);

        if (s > 0) {
            if (tid < 64) {                          // wave 0 only polls
                const int* f = flags + tid * 32;
                while (__hip_atomic_load(f, __ATOMIC_RELAXED,
                                         __HIP_MEMORY_SCOPE_AGENT) < s) {}
            }
            __syncthreads();                         // release + ordering
            asm volatile("" ::: "memory");
        }
        const ushort* hin = hbuf + (size_t)s * 32768;
        ushort* hout = hbuf + (size_t)(s + 1) * 32768;

        short8 hb[16];
#pragma unroll
        for (int kc = 0; kc < 16; ++kc)
            hb[kc] = *(const short8*)(hin + (size_t)(kc * 4 + quad) * 512 + bg * 8);
        f32x4 a0 = {};
#pragma unroll
        for (int kc = 0; kc < 16; ++kc)
            a0 = __builtin_amdgcn_mfma_f32_16x16x32_bf16(wfrag[kc], hb[kc], a0, 0, 0, 0);

        float gi = sigm(a0[0] + bf2f(xa.x));
        float gf = sigm(a0[1] + bf2f(xa.y));
        float go = sigm(a0[2] + bf2f(xa.z));
        float gg = tanh_fast(a0[3] + bf2f(xa.w));
        c = gf * c + gi * gg;
        hstage[bg * 8 + jl] = f2bf(go * c);          // no tanh on c (matches ref)

        __syncthreads();                             // hstage complete
        if (tid < 128)
            __hip_atomic_store((ull*)(hout + bn * 512) + tid,
                               ((const ull*)hstage)[tid],
                               __ATOMIC_RELAXED, __HIP_MEMORY_SCOPE_AGENT);
        __syncthreads();                             // drains vmcnt of the stores
        if (tid == 0)
            __hip_atomic_store(&flags[bn * 32], s + 1, __ATOMIC_RELAXED,
                               __HIP_MEMORY_SCOPE_AGENT);
    }

    // final head: h(64) in slot 64
    if (bn == 0) {
        if (tid < 64) {
            while (__hip_atomic_load(&flags[tid * 32], __ATOMIC_RELAXED,
                                     __HIP_MEMORY_SCOPE_AGENT) < 64) {}
        }
        __syncthreads();
        asm volatile("" ::: "memory");
        const ushort* hb64 = hbuf + (size_t)64 * 32768;
        int b = tid & 63, part = tid >> 6;
        float acc = 0.f;
#pragma unroll
        for (int g8 = 0; g8 < 8; ++g8) {
            int grp = part * 8 + g8;
            const ushort* hp = hb64 + grp * 512 + b * 8;
            const float* wd = W_dec + grp * 8;
#pragma unroll
            for (int half = 0; half < 2; ++half) {
                ull u = *(const ull*)(hp + half * 4);
                acc += bf2f((ushort)u) * wd[half * 4]
                     + bf2f((ushort)(u >> 16)) * wd[half * 4 + 1]
                     + bf2f((ushort)(u >> 32)) * wd[half * 4 + 2]
                     + bf2f((ushort)(u >> 48)) * wd[half * 4 + 3];
            }
        }
        fred[part][b] = acc;
        __syncthreads();
        if (tid < 64) {
            float a = 0.f;
#pragma unroll
            for (int p = 0; p < 8; ++p) a += fred[p][tid];
            float output = sigm(a + b_dec[0]);
            float gate   = sigm(g_logit[tid] * (1.0f / 64.f) + b_gate[0]);
            float ddp    = sigm(dd_logit[tid] + b_dd[0]);
            out[tid] = output * gate + ddp * (1.f - gate);
        }
    }
}

extern "C" void kernel_launch(void* const* d_in, const int* in_sizes, int n_in,
                              void* d_out, int out_size, void* d_ws, size_t ws_size,
                              hipStream_t stream) {
    const float* v_feat   = (const float*)d_in[0];
    const int*   category = (const int*)d_in[1];
    const float* W_enc    = (const float*)d_in[2];
    const float* b_enc    = (const float*)d_in[3];
    const float* Wx       = (const float*)d_in[4];
    const float* bx       = (const float*)d_in[5];
    const float* Wh       = (const float*)d_in[6];
    const float* bh       = (const float*)d_in[7];
    const float* cat_emb  = (const float*)d_in[8];
    const float* W_dec    = (const float*)d_in[9];
    const float* b_dec    = (const float*)d_in[10];
    const float* proto    = (const float*)d_in[11];
    const float* W_dd     = (const float*)d_in[12];
    const float* b_dd     = (const float*)d_in[13];
    const float* W_gate   = (const float*)d_in[14];
    const float* b_gate   = (const float*)d_in[15];
    float* out = (float*)d_out;

    char* ws = (char*)d_ws;
    ushort* xg       = (ushort*)(ws + 0);          // 16 MB bf16 [s][b][n']
    ushort* v_bf16   = (ushort*)(ws + 0);          // overlaps xg (k_dot before GEMM2)
    ushort* fuse     = (ushort*)(ws + 16777216);   // 4 MB
    ushort* Whr      = (ushort*)(ws + 20971520);   // 2 MB
    ushort* Wenc_t   = (ushort*)(ws + 23068672);   // 2 MB
    ushort* Wx_t     = (ushort*)(ws + 25165824);   // 2 MB
    ushort* proto_bf = (ushort*)(ws + 27262976);   // 128 KB
    float*  dots     = (float*)(ws + 27394048);    // 512 KB
    float*  n2       = (float*)(ws + 27918336);    // 16 KB
    float*  gpart    = (float*)(ws + 27934720);    // 16 KB
    float*  p2       = (float*)(ws + 27951104);    // 512 B
    float*  bxh      = (float*)(ws + 27951616);    // 8 KB
    int*    flags    = (int*)(ws + 27959808);      // 8 KB (64 x 128B lines)
    float*  dd_logit = (float*)(ws + 27967744);    // 256 B
    float*  g_logit  = (float*)(ws + 27968000);    // 256 B
    ushort* hbuf     = (ushort*)(ws + 27968256);   // 65 x 64 KB rotating h

    k_prep<<<12382, 256, 0, stream>>>(v_feat, proto, bx, bh, W_enc, Wx, Wh, W_gate,
                                      v_bf16, proto_bf, bxh, Wenc_t, Wx_t, Whr,
                                      n2, gpart, p2, hbuf, flags);

    k_gemm_mfma<<<dim3(4, 32), 256, 0, stream>>>(v_bf16, Wenc_t, 4096, 512, 2048,
                                                 b_enc, cat_emb, category, fuse, 0);
    k_dot<<<64, 256, 0, stream>>>(v_bf16, proto_bf, dots);
    k_dd<<<64, 256, 0, stream>>>(dots, n2, p2, W_dd, gpart, dd_logit, g_logit);

    k_gemm_mfma<<<dim3(16, 32), 256, 0, stream>>>(fuse, Wx_t, 4096, 2048, 512,
                                                  bxh, nullptr, nullptr, xg, 1);

    k_lstm_persist<<<64, 512, 0, stream>>>(xg, Whr, hbuf, flags,
                                           W_dec, b_dec, dd_logit, b_dd,
                                           g_logit, b_gate, out);
}